// Round 10
// baseline (2527.358 us; speedup 1.0000x reference)
//
#include <hip/hip_runtime.h>

typedef unsigned short u16;
typedef unsigned int   u32;
typedef __attribute__((ext_vector_type(8))) short bf16x8;
typedef __attribute__((ext_vector_type(4))) float f32x4;

#define NB 64
#define TT 256
#define FF 1024
#define HH 1024
#define KK 2048
#define GG 4096
#define NBLK 256

// ws layout in u16 units
#define WPACK_SZ  (KK*GG)                    // 8388608 u16 = 16 MB
#define XPACK_SZ  ((size_t)NB*TT*FF)         // 16777216 u16 = 32 MB
#define HPACK_SZ  (2*4*32*64*8)              // 131072 u16 = 256 KB (double buffer)
#define FLAGS_SZ  (4*64*4)                   // u32: 4 rt-groups x 64 flags, 16B stride

__device__ __forceinline__ u16 f2bf(float f) {
  u32 u = __float_as_uint(f);
  u32 r = (u + 0x7FFFu + ((u >> 16) & 1u)) >> 16;
  return (u16)r;
}

// Pack W [K=2048][G=4096] fp32 -> B-fragment order:
// wp[((ct*64 + kt)*64 + l)*8 + j] = bf16( W[kt*32 + (l>>4)*8 + j][ct*16 + (l&15)] )
__global__ void pack_w(const float* __restrict__ W, u16* __restrict__ wp) {
  int tid = blockIdx.x * blockDim.x + threadIdx.x;   // 524288 threads
  if (tid >= (KK * GG / 16)) return;
  int j  = tid & 7;
  int g  = (tid >> 3) & 3;
  int kt = (tid >> 5) & 63;
  int ct = tid >> 11;                                // 0..255
  int k  = kt * 32 + g * 8 + j;
  const float* src = W + (size_t)k * GG + ct * 16;
  u16* dst = wp + (size_t)(ct * 64 + kt) * 512 + j;
  float4 v0 = *(const float4*)(src + 0);
  float4 v1 = *(const float4*)(src + 4);
  float4 v2 = *(const float4*)(src + 8);
  float4 v3 = *(const float4*)(src + 12);
  float vv[16] = {v0.x,v0.y,v0.z,v0.w, v1.x,v1.y,v1.z,v1.w,
                  v2.x,v2.y,v2.z,v2.w, v3.x,v3.y,v3.z,v3.w};
  #pragma unroll
  for (int c = 0; c < 16; ++c) dst[(size_t)(g * 16 + c) * 8] = f2bf(vv[c]);
}

// Pack x [N][T][F] fp32 -> A-fragment order per (t, rt):
// xp[(((t*4 + rt)*32 + kt)*64 + l)*8 + j] = bf16( x[16rt + (l&15)][t][kt*32 + (l>>4)*8 + j] )
__global__ void pack_x(const float* __restrict__ X, u16* __restrict__ xp) {
  int tid = blockIdx.x * blockDim.x + threadIdx.x;   // 2097152 threads
  if (tid >= (int)(NB * TT * FF / 8)) return;
  int l  = tid & 63;
  int kt = (tid >> 6) & 31;
  int rt = (tid >> 11) & 3;
  int t  = tid >> 13;                                // 0..255
  int n  = rt * 16 + (l & 15);
  int f  = kt * 32 + (l >> 4) * 8;
  const float* src = X + (size_t)n * TT * FF + (size_t)t * FF + f;
  float4 a = *(const float4*)(src);
  float4 b = *(const float4*)(src + 4);
  u16 tmp[8] = { f2bf(a.x), f2bf(a.y), f2bf(a.z), f2bf(a.w),
                 f2bf(b.x), f2bf(b.y), f2bf(b.z), f2bf(b.w) };
  *(uint4*)(xp + (size_t)((t * 4 + rt) * 32 + kt) * 512 + l * 8) = *(uint4*)tmp;
}

// zero barrier flags through the coherence point (ws is poisoned 0xAA; stale
// flags from a previous replay would open barriers spuriously)
__global__ void init_state(u32* __restrict__ flags) {
  int tid = threadIdx.x;
  #pragma unroll
  for (int i = 0; i < 4; ++i)
    __hip_atomic_store(&flags[i * 256 + tid], 0u, __ATOMIC_RELAXED,
                       __HIP_MEMORY_SCOPE_AGENT);
}

__launch_bounds__(256, 1)
__global__ void lstm_main(const u16* __restrict__ wp, const u16* __restrict__ xp,
                          u32* __restrict__ hp32, const float* __restrict__ bias,
                          float* __restrict__ z, float* __restrict__ hout,
                          float* __restrict__ memout, u32* flags) {
  const int b   = blockIdx.x;        // 256 blocks, all co-resident
  const int cgi = b & 63;            // col-group: 16 h-cols
  const int rt  = b >> 6;            // row-tile: 16 batch rows -> barrier group
  const int w   = threadIdx.x >> 6;  // wave = gate index 0..3
  const int l   = threadIdx.x & 63;
  const int ct  = w * 64 + cgi;      // global col-tile 0..255

  const u16* bp = wp + (size_t)ct * 32768 + l * 8;   // 64 kt * 512 per col-tile
  const float bv = bias[ct * 16 + (l & 15)];
  u32* gf = flags + rt * 256;        // this rt-group's 64 flags, stride 4 u32

  __shared__ u32   hs32[8192];       // 32 KB staged h fragments (this rt group)
  __shared__ float gl[4][16][16];    // gate tiles for the combine

  const int tid = threadIdx.x;
  const int er  = tid >> 4;          // 0..15 epilogue row
  const int ec  = tid & 15;          // 0..15 epilogue col
  const int m   = rt * 16 + er;      // batch row
  const int col = cgi * 16 + ec;     // col within gate [0,1024)
  // hp u32 slot for the (even) col pair this thread's pair-store covers
  const int col0 = col & ~1;
  const int kt2  = col0 >> 5;
  const int g2   = (col0 >> 3) & 3;
  const int l2   = er | (g2 << 4);
  const int cbase = kt2 * 256 + l2 * 4 + ((col0 & 7) >> 1);  // u32 units

  float memv = 0.0f;                 // cell state lives in a register

  // ---- prologue: x-GEMM(0) into the "current" x accumulators ----
  f32x4 cx0 = {bv, bv, bv, bv};
  f32x4 cx1 = {0.f, 0.f, 0.f, 0.f};
  {
    const u16* ax = xp + (size_t)((0 * 4 + rt) * 32) * 512 + l * 8;
    #pragma unroll
    for (int kt = 0; kt < 32; kt += 2) {
      bf16x8 a0 = *(const bf16x8*)(ax + (size_t)kt * 512);
      bf16x8 b0 = *(const bf16x8*)(bp + (size_t)kt * 512);
      bf16x8 a1 = *(const bf16x8*)(ax + (size_t)(kt + 1) * 512);
      bf16x8 b1 = *(const bf16x8*)(bp + (size_t)(kt + 1) * 512);
      cx0 = __builtin_amdgcn_mfma_f32_16x16x32_bf16(a0, b0, cx0, 0, 0, 0);
      cx1 = __builtin_amdgcn_mfma_f32_16x16x32_bf16(a1, b1, cx1, 0, 0, 0);
    }
  }

  for (int t = 0; t < TT; ++t) {
    const int p = t & 1;             // h(t) lives in buffer p (written last step)
    // x fragments for step t+1 (pipelined one step ahead)
    const u16* axn = xp + (size_t)(((t + 1) * 4 + rt) * 32) * 512 + l * 8;
    const bool lastT = (t == TT - 1);

    f32x4 nx0 = {bv, bv, bv, bv};    // next-step x accumulators
    f32x4 nx1 = {0.f, 0.f, 0.f, 0.f};
    f32x4 ah0 = {0.f, 0.f, 0.f, 0.f};// h accumulators for this step
    f32x4 ah1 = {0.f, 0.f, 0.f, 0.f};

    u32 tmpv[32];
    if (t != 0) {
      // ---- wait for h(t): coalesced poll of the 64 group flags ----
      const u32 tgt = (u32)t;
      for (;;) {
        u32 v = __hip_atomic_load(&gf[l * 4], __ATOMIC_RELAXED,
                                  __HIP_MEMORY_SCOPE_AGENT);
        if (l == cgi) v = tgt;       // own arrival known locally
        if (!__any((int)(v < tgt))) break;
        __builtin_amdgcn_s_sleep(1);
      }
      // ---- issue the 32 h-copy loads (latency hidden by x-MFMAs below) ----
      const u32* hsrc = hp32 + (size_t)(p * 4 + rt) * 8192;
      #pragma unroll
      for (int i = 0; i < 32; ++i)
        tmpv[i] = __hip_atomic_load(hsrc + i * 256 + tid, __ATOMIC_RELAXED,
                                    __HIP_MEMORY_SCOPE_AGENT);
    }

    // ---- x(t+1) head: kt 0..7, runs under the copy-load latency ----
    if (!lastT) {
      #pragma unroll
      for (int kt = 0; kt < 8; kt += 2) {
        bf16x8 a0 = *(const bf16x8*)(axn + (size_t)kt * 512);
        bf16x8 b0 = *(const bf16x8*)(bp + (size_t)kt * 512);
        bf16x8 a1 = *(const bf16x8*)(axn + (size_t)(kt + 1) * 512);
        bf16x8 b1 = *(const bf16x8*)(bp + (size_t)(kt + 1) * 512);
        nx0 = __builtin_amdgcn_mfma_f32_16x16x32_bf16(a0, b0, nx0, 0, 0, 0);
        nx1 = __builtin_amdgcn_mfma_f32_16x16x32_bf16(a1, b1, nx1, 0, 0, 0);
      }
    }

    if (t != 0) {
      // ---- land the copied h fragments in LDS ----
      #pragma unroll
      for (int i = 0; i < 32; ++i)
        hs32[i * 256 + tid] = tmpv[i];
      __syncthreads();
    }

    // ---- merged tail: x(t+1) kt 8..31 interleaved with h(t) kt 0..31 ----
    const char* hb = (const char*)hs32 + l * 16;
    #pragma unroll
    for (int i = 0; i < 24; i += 2) {
      if (!lastT) {
        bf16x8 a0 = *(const bf16x8*)(axn + (size_t)(8 + i) * 512);
        bf16x8 b0 = *(const bf16x8*)(bp + (size_t)(8 + i) * 512);
        bf16x8 a1 = *(const bf16x8*)(axn + (size_t)(9 + i) * 512);
        bf16x8 b1 = *(const bf16x8*)(bp + (size_t)(9 + i) * 512);
        nx0 = __builtin_amdgcn_mfma_f32_16x16x32_bf16(a0, b0, nx0, 0, 0, 0);
        nx1 = __builtin_amdgcn_mfma_f32_16x16x32_bf16(a1, b1, nx1, 0, 0, 0);
      }
      if (t != 0) {
        bf16x8 a0 = *(const bf16x8*)(hb + (size_t)i * 1024);
        bf16x8 b0 = *(const bf16x8*)(bp + (size_t)(32 + i) * 512);
        bf16x8 a1 = *(const bf16x8*)(hb + (size_t)(i + 1) * 1024);
        bf16x8 b1 = *(const bf16x8*)(bp + (size_t)(33 + i) * 512);
        ah0 = __builtin_amdgcn_mfma_f32_16x16x32_bf16(a0, b0, ah0, 0, 0, 0);
        ah1 = __builtin_amdgcn_mfma_f32_16x16x32_bf16(a1, b1, ah1, 0, 0, 0);
      }
    }
    if (t != 0) {
      #pragma unroll
      for (int i = 24; i < 32; i += 2) {
        bf16x8 a0 = *(const bf16x8*)(hb + (size_t)i * 1024);
        bf16x8 b0 = *(const bf16x8*)(bp + (size_t)(32 + i) * 512);
        bf16x8 a1 = *(const bf16x8*)(hb + (size_t)(i + 1) * 1024);
        bf16x8 b1 = *(const bf16x8*)(bp + (size_t)(33 + i) * 512);
        ah0 = __builtin_amdgcn_mfma_f32_16x16x32_bf16(a0, b0, ah0, 0, 0, 0);
        ah1 = __builtin_amdgcn_mfma_f32_16x16x32_bf16(a1, b1, ah1, 0, 0, 0);
      }
    }

    // C-layout: col = l&15, row = (l>>4)*4 + r  (HW-verified)
    #pragma unroll
    for (int r = 0; r < 4; ++r)
      gl[w][(l >> 4) * 4 + r][l & 15] = (cx0[r] + cx1[r]) + (ah0[r] + ah1[r]);
    __syncthreads();

    // gate combine: one (m,col) element per thread
    float ai = gl[0][er][ec], af = gl[1][er][ec];
    float ao = gl[2][er][ec], ag = gl[3][er][ec];
    float si = 1.f / (1.f + __expf(-ai));
    float sf = 1.f / (1.f + __expf(-af));
    float so = 1.f / (1.f + __expf(-ao));
    float tg = 1.f - 2.f / (__expf(2.f * ag) + 1.f);   // safe tanh
    memv = sf * memv + si * tg;
    float th = 1.f - 2.f / (__expf(2.f * memv) + 1.f); // safe tanh
    float h = so * th;

    // publish h as bf16 pairs through the coherence point (write-through)
    float hn = __shfl_xor(h, 1);     // partner col's h
    if ((ec & 1) == 0) {
      u32 pair = (u32)f2bf(h) | ((u32)f2bf(hn) << 16);
      __hip_atomic_store(&hp32[(size_t)((p ^ 1) * 4 + rt) * 8192 + cbase], pair,
                         __ATOMIC_RELAXED, __HIP_MEMORY_SCOPE_AGENT);
    }

    if (!lastT) {
      // publish: syncthreads drains vmcnt(0) -> hp data at coherence point.
      // (also separates this step's hs32/gl reads from next step's writes)
      __syncthreads();
      if (tid == 0)
        __hip_atomic_store(&gf[cgi * 4], (u32)(t + 1), __ATOMIC_RELAXED,
                           __HIP_MEMORY_SCOPE_AGENT);
    }

    // z-store AFTER the flag publish: not on anyone's critical path
    z[((size_t)m * TT + t) * HH + col] = h;
    if (lastT) hout[(size_t)m * HH + col] = h;

    // rotate the pipelined x accumulators
    cx0 = nx0;
    cx1 = nx1;
  }
  memout[(size_t)m * HH + col] = memv;
}

extern "C" void kernel_launch(void* const* d_in, const int* in_sizes, int n_in,
                              void* d_out, int out_size, void* d_ws, size_t ws_size,
                              hipStream_t stream) {
  const float* x    = (const float*)d_in[0];
  const float* W    = (const float*)d_in[1];
  const float* bias = (const float*)d_in[2];

  float* z      = (float*)d_out;
  float* hout   = z + (size_t)NB * TT * HH;
  float* memout = hout + (size_t)NB * HH;

  u16* wp = (u16*)d_ws;
  u16* xp = wp + WPACK_SZ;
  u16* hp = xp + XPACK_SZ;
  u32* flags = (u32*)(hp + HPACK_SZ);

  hipLaunchKernelGGL(pack_w, dim3(2048), dim3(256), 0, stream, W, wp);
  hipLaunchKernelGGL(pack_x, dim3(8192), dim3(256), 0, stream, x, xp);
  hipLaunchKernelGGL(init_state, dim3(1), dim3(256), 0, stream, flags);

  hipLaunchKernelGGL(lstm_main, dim3(NBLK), dim3(256), 0, stream,
                     wp, xp, (u16*)hp ? (u32*)hp : (u32*)hp, bias, z, hout, memout, flags);
}

// Round 12
// 2404.307 us; speedup vs baseline: 1.0512x; 1.0512x over previous
//
#include <hip/hip_runtime.h>

typedef unsigned short u16;
typedef unsigned int   u32;
typedef unsigned long long u64;
typedef __attribute__((ext_vector_type(8))) short bf16x8;
typedef __attribute__((ext_vector_type(4))) float f32x4;

#define NB 64
#define TT 256
#define FF 1024
#define HH 1024
#define KK 2048
#define GG 4096
#define NBLK 256

// ws layout in u16 units
#define WPACK_SZ  (KK*GG)                    // 8388608 u16 = 16 MB
#define XPACK_SZ  ((size_t)NB*TT*FF)         // 16777216 u16 = 32 MB
#define HPACK_SZ  (2*4*32*64*8)              // 131072 u16 = 256 KB (double buffer)
#define FLAGS_U32 1024                       // 4 KB: 4 rt-groups x 64 flags, 16B stride
#define RING_U64  (256*4*1024)               // 8 MB: 256 pairs x 4 slots x 1024 words

__device__ __forceinline__ u16 f2bf(float f) {
  u32 u = __float_as_uint(f);
  u32 r = (u + 0x7FFFu + ((u >> 16) & 1u)) >> 16;
  return (u16)r;
}

// Pack W [K=2048][G=4096] fp32 -> B-fragment order:
// wp[((ct*64 + kt)*64 + l)*8 + j] = bf16( W[kt*32 + (l>>4)*8 + j][ct*16 + (l&15)] )
__global__ void pack_w(const float* __restrict__ W, u16* __restrict__ wp) {
  int tid = blockIdx.x * blockDim.x + threadIdx.x;   // 524288 threads
  if (tid >= (KK * GG / 16)) return;
  int j  = tid & 7;
  int g  = (tid >> 3) & 3;
  int kt = (tid >> 5) & 63;
  int ct = tid >> 11;                                // 0..255
  int k  = kt * 32 + g * 8 + j;
  const float* src = W + (size_t)k * GG + ct * 16;
  u16* dst = wp + (size_t)(ct * 64 + kt) * 512 + j;
  float4 v0 = *(const float4*)(src + 0);
  float4 v1 = *(const float4*)(src + 4);
  float4 v2 = *(const float4*)(src + 8);
  float4 v3 = *(const float4*)(src + 12);
  float vv[16] = {v0.x,v0.y,v0.z,v0.w, v1.x,v1.y,v1.z,v1.w,
                  v2.x,v2.y,v2.z,v2.w, v3.x,v3.y,v3.z,v3.w};
  #pragma unroll
  for (int c = 0; c < 16; ++c) dst[(size_t)(g * 16 + c) * 8] = f2bf(vv[c]);
}

// Pack x [N][T][F] fp32 -> A-fragment order per (t, rt):
// xp[(((t*4 + rt)*32 + kt)*64 + l)*8 + j] = bf16( x[16rt + (l&15)][t][kt*32 + (l>>4)*8 + j] )
__global__ void pack_x(const float* __restrict__ X, u16* __restrict__ xp) {
  int tid = blockIdx.x * blockDim.x + threadIdx.x;   // 2097152 threads
  if (tid >= (int)(NB * TT * FF / 8)) return;
  int l  = tid & 63;
  int kt = (tid >> 6) & 31;
  int rt = (tid >> 11) & 3;
  int t  = tid >> 13;                                // 0..255
  int n  = rt * 16 + (l & 15);
  int f  = kt * 32 + (l >> 4) * 8;
  const float* src = X + (size_t)n * TT * FF + (size_t)t * FF + f;
  float4 a = *(const float4*)(src);
  float4 b = *(const float4*)(src + 4);
  u16 tmp[8] = { f2bf(a.x), f2bf(a.y), f2bf(a.z), f2bf(a.w),
                 f2bf(b.x), f2bf(b.y), f2bf(b.z), f2bf(b.w) };
  *(uint4*)(xp + (size_t)((t * 4 + rt) * 32 + kt) * 512 + l * 8) = *(uint4*)tmp;
}

// zero ring tags + flags through the coherence point each launch (ws poisoned
// 0xAA; stale tags/flags from a previous replay must never match)
__global__ void init_state(u32* __restrict__ flags, u64* __restrict__ ring) {
  int gid = blockIdx.x * blockDim.x + threadIdx.x;   // 4096*256 = 1048576
  __hip_atomic_store(&ring[gid], 0ull, __ATOMIC_RELAXED,
                     __HIP_MEMORY_SCOPE_AGENT);
  if (gid < FLAGS_U32)
    __hip_atomic_store(&flags[gid], 0u, __ATOMIC_RELAXED,
                       __HIP_MEMORY_SCOPE_AGENT);
}

__launch_bounds__(256, 2)   // 2 blocks/CU: consumer + producer co-resident
__global__ void lstm_main(const u16* __restrict__ wp, const u16* __restrict__ xp,
                          u32* __restrict__ hp32, const float* __restrict__ bias,
                          float* __restrict__ z, float* __restrict__ hout,
                          float* __restrict__ memout, u32* flags,
                          u64* __restrict__ ring) {
  const int role = (blockIdx.x >= NBLK);   // 0 = h-consumer, 1 = x-producer
  const int b    = blockIdx.x & (NBLK - 1);
  const int cgi  = b & 63;                 // col-group: 16 h-cols
  const int rt   = b >> 6;                 // row-tile: 16 batch rows
  const int w    = threadIdx.x >> 6;       // wave = gate index 0..3
  const int l    = threadIdx.x & 63;
  const int ct   = w * 64 + cgi;           // global col-tile 0..255

  const u16* bp = wp + (size_t)ct * 32768 + l * 8;
  const float bv = bias[ct * 16 + (l & 15)];
  u32* gf = flags + rt * 256;              // this rt-group's 64 flags
  u64* rg = ring + (size_t)b * 4096;       // this pair's private 4-slot ring

  __shared__ u32   hs32[8192];             // 32 KB staged h fragments
  __shared__ float gl[4][16][16];          // ah gate tiles

  if (role) {
    // ================= x-producer: a_x(t) = bias + x(t) @ W_x =================
    for (int t = 0; t < TT; ++t) {
      if (t >= 4) {
        // backpressure: overwrite slot t&3 (holding a_x(t-4)) only after every
        // consumer in the group finished step t-4 (flag >= t-3).
        const u32 need = (u32)(t - 3);
        for (;;) {
          u32 v = __hip_atomic_load(&gf[l * 4], __ATOMIC_RELAXED,
                                    __HIP_MEMORY_SCOPE_AGENT);
          if (!__any((int)(v < need))) break;
          __builtin_amdgcn_s_sleep(2);
        }
      }
      const u16* ax = xp + (size_t)((t * 4 + rt) * 32) * 512 + l * 8;
      f32x4 acc0 = {bv, bv, bv, bv};
      f32x4 acc1 = {0.f, 0.f, 0.f, 0.f};
      #pragma unroll
      for (int kt = 0; kt < 32; kt += 2) {
        bf16x8 a0 = *(const bf16x8*)(ax + (size_t)kt * 512);
        bf16x8 b0 = *(const bf16x8*)(bp + (size_t)kt * 512);
        bf16x8 a1 = *(const bf16x8*)(ax + (size_t)(kt + 1) * 512);
        bf16x8 b1 = *(const bf16x8*)(bp + (size_t)(kt + 1) * 512);
        acc0 = __builtin_amdgcn_mfma_f32_16x16x32_bf16(a0, b0, acc0, 0, 0, 0);
        acc1 = __builtin_amdgcn_mfma_f32_16x16x32_bf16(a1, b1, acc1, 0, 0, 0);
      }
      // publish the 16x16 gate tile as tagged u64 words (tag = t+1)
      // C-layout: col = l&15, row = (l>>4)*4 + r
      u64* dst = rg + (size_t)(t & 3) * 1024 + w * 256 + (l & 15);
      const u64 tagw = (u64)(u32)(t + 1) << 32;
      #pragma unroll
      for (int r = 0; r < 4; ++r) {
        float s = acc0[r] + acc1[r];
        __hip_atomic_store(&dst[(size_t)(((l >> 4) * 4 + r) * 16)],
                           tagw | (u64)__float_as_uint(s),
                           __ATOMIC_RELAXED, __HIP_MEMORY_SCOPE_AGENT);
      }
    }
    return;
  }

  // ================= h-consumer: serial recurrence =================
  const int tid = threadIdx.x;
  const int er  = tid >> 4;          // 0..15 epilogue row
  const int ec  = tid & 15;          // 0..15 epilogue col
  const int m   = rt * 16 + er;      // batch row
  const int col = cgi * 16 + ec;     // col within gate [0,1024)
  const int col0 = col & ~1;
  const int kt2  = col0 >> 5;
  const int g2   = (col0 >> 3) & 3;
  const int l2   = er | (g2 << 4);
  const int cbase = kt2 * 256 + l2 * 4 + ((col0 & 7) >> 1);  // u32 units

  float memv = 0.0f;

  for (int t = 0; t < TT; ++t) {
    const int p = t & 1;             // h(t) lives in buffer p

    if (t != 0) {
      // ---- wait for h(t): coalesced poll of the 64 group flags ----
      const u32 tgt = (u32)t;
      for (;;) {
        u32 v = __hip_atomic_load(&gf[l * 4], __ATOMIC_RELAXED,
                                  __HIP_MEMORY_SCOPE_AGENT);
        if (l == cgi) v = tgt;       // own arrival known locally
        if (!__any((int)(v < tgt))) break;
        __builtin_amdgcn_s_sleep(1);
      }
    }

    // ---- early-issue this thread's 4 tagged a_x words (producer is ahead;
    // latency hides under h-copy + h-GEMM; only 8 VGPRs live) ----
    const u64* axsrc = rg + (size_t)(t & 3) * 1024 + er * 16 + ec;
    u64 axw0 = __hip_atomic_load(&axsrc[0],   __ATOMIC_RELAXED, __HIP_MEMORY_SCOPE_AGENT);
    u64 axw1 = __hip_atomic_load(&axsrc[256], __ATOMIC_RELAXED, __HIP_MEMORY_SCOPE_AGENT);
    u64 axw2 = __hip_atomic_load(&axsrc[512], __ATOMIC_RELAXED, __HIP_MEMORY_SCOPE_AGENT);
    u64 axw3 = __hip_atomic_load(&axsrc[768], __ATOMIC_RELAXED, __HIP_MEMORY_SCOPE_AGENT);

    f32x4 acc2 = {0.f, 0.f, 0.f, 0.f};
    f32x4 acc3 = {0.f, 0.f, 0.f, 0.f};
    if (t != 0) {
      // ---- copy h fragments to LDS via coherence-point loads ----
      const u32* hsrc = hp32 + (size_t)(p * 4 + rt) * 8192;
      u32 tmpv[32];
      #pragma unroll
      for (int i = 0; i < 32; ++i)
        tmpv[i] = __hip_atomic_load(hsrc + i * 256 + tid, __ATOMIC_RELAXED,
                                    __HIP_MEMORY_SCOPE_AGENT);
      #pragma unroll
      for (int i = 0; i < 32; ++i)
        hs32[i * 256 + tid] = tmpv[i];
      __syncthreads();

      // ---- h-GEMM (A from LDS, W_h streamed from L2) ----
      const char* hb = (const char*)hs32 + l * 16;
      #pragma unroll
      for (int kt = 0; kt < 32; kt += 2) {
        bf16x8 a0 = *(const bf16x8*)(hb + (size_t)kt * 1024);
        bf16x8 b0 = *(const bf16x8*)(bp + (size_t)(32 + kt) * 512);
        bf16x8 a1 = *(const bf16x8*)(hb + (size_t)(kt + 1) * 1024);
        bf16x8 b1 = *(const bf16x8*)(bp + (size_t)(33 + kt) * 512);
        acc2 = __builtin_amdgcn_mfma_f32_16x16x32_bf16(a0, b0, acc2, 0, 0, 0);
        acc3 = __builtin_amdgcn_mfma_f32_16x16x32_bf16(a1, b1, acc3, 0, 0, 0);
      }
    }

    // C-layout: col = l&15, row = (l>>4)*4 + r
    #pragma unroll
    for (int r = 0; r < 4; ++r)
      gl[w][(l >> 4) * 4 + r][l & 15] = acc2[r] + acc3[r];
    __syncthreads();

    // ---- validate a_x tags; retry stragglers (SPSC, normally instant) ----
    const u32 tg = (u32)(t + 1);
    while ((u32)(axw0 >> 32) != tg || (u32)(axw1 >> 32) != tg ||
           (u32)(axw2 >> 32) != tg || (u32)(axw3 >> 32) != tg) {
      if ((u32)(axw0 >> 32) != tg)
        axw0 = __hip_atomic_load(&axsrc[0],   __ATOMIC_RELAXED, __HIP_MEMORY_SCOPE_AGENT);
      if ((u32)(axw1 >> 32) != tg)
        axw1 = __hip_atomic_load(&axsrc[256], __ATOMIC_RELAXED, __HIP_MEMORY_SCOPE_AGENT);
      if ((u32)(axw2 >> 32) != tg)
        axw2 = __hip_atomic_load(&axsrc[512], __ATOMIC_RELAXED, __HIP_MEMORY_SCOPE_AGENT);
      if ((u32)(axw3 >> 32) != tg)
        axw3 = __hip_atomic_load(&axsrc[768], __ATOMIC_RELAXED, __HIP_MEMORY_SCOPE_AGENT);
      __builtin_amdgcn_s_sleep(1);
    }

    // ---- gate combine: a = a_x (bias included) + a_h ----
    float ai = __uint_as_float((u32)axw0) + gl[0][er][ec];
    float af = __uint_as_float((u32)axw1) + gl[1][er][ec];
    float ao = __uint_as_float((u32)axw2) + gl[2][er][ec];
    float ag = __uint_as_float((u32)axw3) + gl[3][er][ec];
    float si = 1.f / (1.f + __expf(-ai));
    float sf = 1.f / (1.f + __expf(-af));
    float so = 1.f / (1.f + __expf(-ao));
    float tgh = 1.f - 2.f / (__expf(2.f * ag) + 1.f);   // safe tanh
    memv = sf * memv + si * tgh;
    float th = 1.f - 2.f / (__expf(2.f * memv) + 1.f);  // safe tanh
    float h = so * th;

    // publish h as bf16 pairs through the coherence point
    float hn = __shfl_xor(h, 1);
    if ((ec & 1) == 0) {
      u32 pair = (u32)f2bf(h) | ((u32)f2bf(hn) << 16);
      __hip_atomic_store(&hp32[(size_t)((p ^ 1) * 4 + rt) * 8192 + cbase], pair,
                         __ATOMIC_RELAXED, __HIP_MEMORY_SCOPE_AGENT);
    }

    if (t < TT - 1) {
      __syncthreads();               // drains vmcnt(0): hp at coherence point
      if (tid == 0)
        __hip_atomic_store(&gf[cgi * 4], (u32)(t + 1), __ATOMIC_RELAXED,
                           __HIP_MEMORY_SCOPE_AGENT);
    }

    // z-store AFTER the flag publish: not on anyone's critical path
    z[((size_t)m * TT + t) * HH + col] = h;
    if (t == TT - 1) hout[(size_t)m * HH + col] = h;
  }
  memout[(size_t)m * HH + col] = memv;
}

extern "C" void kernel_launch(void* const* d_in, const int* in_sizes, int n_in,
                              void* d_out, int out_size, void* d_ws, size_t ws_size,
                              hipStream_t stream) {
  const float* x    = (const float*)d_in[0];
  const float* W    = (const float*)d_in[1];
  const float* bias = (const float*)d_in[2];

  float* z      = (float*)d_out;
  float* hout   = z + (size_t)NB * TT * HH;
  float* memout = hout + (size_t)NB * HH;

  u16* wp = (u16*)d_ws;
  u16* xp = wp + WPACK_SZ;
  u16* hp = xp + XPACK_SZ;
  u32* flags = (u32*)(hp + HPACK_SZ);        // 4 KB
  u64* ring  = (u64*)((char*)flags + 4096);  // 8 MB, 8B-aligned

  hipLaunchKernelGGL(pack_w, dim3(2048), dim3(256), 0, stream, W, wp);
  hipLaunchKernelGGL(pack_x, dim3(8192), dim3(256), 0, stream, x, xp);
  hipLaunchKernelGGL(init_state, dim3(4096), dim3(256), 0, stream, flags, ring);

  hipLaunchKernelGGL(lstm_main, dim3(2 * NBLK), dim3(256), 0, stream,
                     wp, xp, (u32*)hp, bias, z, hout, memout, flags, ring);
}

// Round 13
// 1320.362 us; speedup vs baseline: 1.9141x; 1.8209x over previous
//
#include <hip/hip_runtime.h>

typedef unsigned short u16;
typedef unsigned int   u32;
typedef __attribute__((ext_vector_type(8))) short bf16x8;
typedef __attribute__((ext_vector_type(4))) float f32x4;

#define NB 64
#define TT 256
#define FF 1024
#define HH 1024
#define KK 2048
#define GG 4096
#define NBLK 256

// ws layout in u16 units
#define WPACK_SZ  (KK*GG)                    // 8388608 u16 = 16 MB
#define XPACK_SZ  ((size_t)NB*TT*FF)         // 16777216 u16 = 32 MB
#define HPACK_SZ  (2*4*32*64*8)              // 131072 u16 = 256 KB (double buffer)
#define FLAGS_SZ  (4*64*4)                   // u32: 4 rt-groups x 64 flags, 16B stride

__device__ __forceinline__ u16 f2bf(float f) {
  u32 u = __float_as_uint(f);
  u32 r = (u + 0x7FFFu + ((u >> 16) & 1u)) >> 16;
  return (u16)r;
}

// Pack W [K=2048][G=4096] fp32 -> B-fragment order:
// wp[((ct*64 + kt)*64 + l)*8 + j] = bf16( W[kt*32 + (l>>4)*8 + j][ct*16 + (l&15)] )
__global__ void pack_w(const float* __restrict__ W, u16* __restrict__ wp) {
  int tid = blockIdx.x * blockDim.x + threadIdx.x;   // 524288 threads
  if (tid >= (KK * GG / 16)) return;
  int j  = tid & 7;
  int g  = (tid >> 3) & 3;
  int kt = (tid >> 5) & 63;
  int ct = tid >> 11;                                // 0..255
  int k  = kt * 32 + g * 8 + j;
  const float* src = W + (size_t)k * GG + ct * 16;
  u16* dst = wp + (size_t)(ct * 64 + kt) * 512 + j;
  float4 v0 = *(const float4*)(src + 0);
  float4 v1 = *(const float4*)(src + 4);
  float4 v2 = *(const float4*)(src + 8);
  float4 v3 = *(const float4*)(src + 12);
  float vv[16] = {v0.x,v0.y,v0.z,v0.w, v1.x,v1.y,v1.z,v1.w,
                  v2.x,v2.y,v2.z,v2.w, v3.x,v3.y,v3.z,v3.w};
  #pragma unroll
  for (int c = 0; c < 16; ++c) dst[(size_t)(g * 16 + c) * 8] = f2bf(vv[c]);
}

// Pack x [N][T][F] fp32 -> A-fragment order per (t, rt):
// xp[(((t*4 + rt)*32 + kt)*64 + l)*8 + j] = bf16( x[16rt + (l&15)][t][kt*32 + (l>>4)*8 + j] )
__global__ void pack_x(const float* __restrict__ X, u16* __restrict__ xp) {
  int tid = blockIdx.x * blockDim.x + threadIdx.x;   // 2097152 threads
  if (tid >= (int)(NB * TT * FF / 8)) return;
  int l  = tid & 63;
  int kt = (tid >> 6) & 31;
  int rt = (tid >> 11) & 3;
  int t  = tid >> 13;                                // 0..255
  int n  = rt * 16 + (l & 15);
  int f  = kt * 32 + (l >> 4) * 8;
  const float* src = X + (size_t)n * TT * FF + (size_t)t * FF + f;
  float4 a = *(const float4*)(src);
  float4 b = *(const float4*)(src + 4);
  u16 tmp[8] = { f2bf(a.x), f2bf(a.y), f2bf(a.z), f2bf(a.w),
                 f2bf(b.x), f2bf(b.y), f2bf(b.z), f2bf(b.w) };
  *(uint4*)(xp + (size_t)((t * 4 + rt) * 32 + kt) * 512 + l * 8) = *(uint4*)tmp;
}

// zero barrier flags through the coherence point (ws is poisoned 0xAA; stale
// flags from a previous replay would open barriers spuriously)
__global__ void init_state(u32* __restrict__ flags) {
  int tid = threadIdx.x;
  #pragma unroll
  for (int i = 0; i < 4; ++i)
    __hip_atomic_store(&flags[i * 256 + tid], 0u, __ATOMIC_RELAXED,
                       __HIP_MEMORY_SCOPE_AGENT);
}

__launch_bounds__(512, 1)   // 8 waves = 2 waves/SIMD: 2x memory-level parallelism
__global__ void lstm_main(const u16* __restrict__ wp, const u16* __restrict__ xp,
                          u32* __restrict__ hp32, const float* __restrict__ bias,
                          float* __restrict__ z, float* __restrict__ hout,
                          float* __restrict__ memout, u32* flags) {
  const int b   = blockIdx.x;        // 256 blocks, all co-resident
  const int cgi = b & 63;            // col-group: 16 h-cols
  const int rt  = b >> 6;            // row-tile: 16 batch rows -> barrier group
  const int tid = threadIdx.x;
  const int w8  = tid >> 6;          // wave 0..7
  const int g   = w8 & 3;            // gate index
  const int s   = w8 >> 2;           // K-half: kt [16s, 16s+16) of each GEMM
  const int l   = tid & 63;
  const int ct  = g * 64 + cgi;      // global col-tile 0..255

  const u16* bp = wp + (size_t)ct * 32768 + l * 8;   // 64 kt * 512 per col-tile
  const float bv = (s == 0) ? bias[ct * 16 + (l & 15)] : 0.f;
  u32* gf = flags + rt * 256;        // this rt-group's 64 flags, stride 4 u32

  __shared__ u32   hs32[8192];       // 32 KB staged h fragments (this rt group)
  __shared__ float gl[2][4][16][16]; // partial gate tiles (K-half, gate)

  const int er  = tid >> 4;          // 0..15 epilogue row   (valid for tid<256)
  const int ec  = tid & 15;          // 0..15 epilogue col
  const int m   = rt * 16 + er;      // batch row
  const int col = cgi * 16 + ec;     // col within gate [0,1024)
  // hp u32 slot for the (even) col pair this thread's pair-store covers
  const int col0 = col & ~1;
  const int kt2  = col0 >> 5;
  const int g2   = (col0 >> 3) & 3;
  const int l2   = er | (g2 << 4);
  const int cbase = kt2 * 256 + l2 * 4 + ((col0 & 7) >> 1);  // u32 units

  float memv = 0.0f;                 // cell state (tid<256 only)

  for (int t = 0; t < TT; ++t) {
    const int p = t & 1;             // h(t) lives in buffer p (written last step)
    const u16* ax = xp + (size_t)((t * 4 + rt) * 32 + s * 16) * 512 + l * 8;
    const u16* bx = bp + (size_t)(s * 16) * 512;          // x-B frags, this half
    const u16* bh = bp + (size_t)(32 + s * 16) * 512;     // h-B frags, this half

    // ---- x-half GEMM: 16 MFMAs over this wave's K-half ----
    f32x4 acc0 = {bv, bv, bv, bv};
    f32x4 acc1 = {0.f, 0.f, 0.f, 0.f};
    #pragma unroll
    for (int kt = 0; kt < 16; kt += 2) {
      bf16x8 a0 = *(const bf16x8*)(ax + (size_t)kt * 512);
      bf16x8 b0 = *(const bf16x8*)(bx + (size_t)kt * 512);
      bf16x8 a1 = *(const bf16x8*)(ax + (size_t)(kt + 1) * 512);
      bf16x8 b1 = *(const bf16x8*)(bx + (size_t)(kt + 1) * 512);
      acc0 = __builtin_amdgcn_mfma_f32_16x16x32_bf16(a0, b0, acc0, 0, 0, 0);
      acc1 = __builtin_amdgcn_mfma_f32_16x16x32_bf16(a1, b1, acc1, 0, 0, 0);
    }

    if (t != 0) {
      // ---- wait for h(t): coalesced poll of the 64 group flags ----
      const u32 tgt = (u32)t;
      for (;;) {
        u32 v = __hip_atomic_load(&gf[l * 4], __ATOMIC_RELAXED,
                                  __HIP_MEMORY_SCOPE_AGENT);
        if (l == cgi) v = tgt;       // own arrival known locally
        if (!__any((int)(v < tgt))) break;
        __builtin_amdgcn_s_sleep(1);
      }

      // ---- copy h fragments to LDS (512 threads, 16 words each) ----
      const u32* hsrc = hp32 + (size_t)(p * 4 + rt) * 8192;
      u32 tmpv[16];
      #pragma unroll
      for (int i = 0; i < 16; ++i)
        tmpv[i] = __hip_atomic_load(hsrc + i * 512 + tid, __ATOMIC_RELAXED,
                                    __HIP_MEMORY_SCOPE_AGENT);
      #pragma unroll
      for (int i = 0; i < 16; ++i)
        hs32[i * 512 + tid] = tmpv[i];
      __syncthreads();

      // ---- h-half GEMM: 16 MFMAs, A from LDS, B from L2 ----
      const char* hb = (const char*)hs32 + (size_t)(s * 16) * 1024 + l * 16;
      #pragma unroll
      for (int kt = 0; kt < 16; kt += 2) {
        bf16x8 a0 = *(const bf16x8*)(hb + (size_t)kt * 1024);
        bf16x8 b0 = *(const bf16x8*)(bh + (size_t)kt * 512);
        bf16x8 a1 = *(const bf16x8*)(hb + (size_t)(kt + 1) * 1024);
        bf16x8 b1 = *(const bf16x8*)(bh + (size_t)(kt + 1) * 512);
        acc0 = __builtin_amdgcn_mfma_f32_16x16x32_bf16(a0, b0, acc0, 0, 0, 0);
        acc1 = __builtin_amdgcn_mfma_f32_16x16x32_bf16(a1, b1, acc1, 0, 0, 0);
      }
    }

    // C-layout: col = l&15, row = (l>>4)*4 + r  (HW-verified)
    #pragma unroll
    for (int r = 0; r < 4; ++r)
      gl[s][g][(l >> 4) * 4 + r][l & 15] = acc0[r] + acc1[r];
    __syncthreads();

    float h;
    if (tid < 256) {
      // gate combine: sum the two K-half partials per gate
      float ai = gl[0][0][er][ec] + gl[1][0][er][ec];
      float af = gl[0][1][er][ec] + gl[1][1][er][ec];
      float ao = gl[0][2][er][ec] + gl[1][2][er][ec];
      float ag = gl[0][3][er][ec] + gl[1][3][er][ec];
      float si = 1.f / (1.f + __expf(-ai));
      float sf = 1.f / (1.f + __expf(-af));
      float so = 1.f / (1.f + __expf(-ao));
      float tg = 1.f - 2.f / (__expf(2.f * ag) + 1.f);   // safe tanh
      memv = sf * memv + si * tg;
      float th = 1.f - 2.f / (__expf(2.f * memv) + 1.f); // safe tanh
      h = so * th;

      // publish h as bf16 pairs through the coherence point (write-through)
      float hn = __shfl_xor(h, 1);   // partner col's h
      if ((ec & 1) == 0) {
        u32 pair = (u32)f2bf(h) | ((u32)f2bf(hn) << 16);
        __hip_atomic_store(&hp32[(size_t)((p ^ 1) * 4 + rt) * 8192 + cbase], pair,
                           __ATOMIC_RELAXED, __HIP_MEMORY_SCOPE_AGENT);
      }
    }

    if (t < TT - 1) {
      // publish: syncthreads drains vmcnt(0) -> hp data at coherence point.
      // (also separates this step's hs32/gl reads from next step's writes)
      __syncthreads();
      if (tid == 0)
        __hip_atomic_store(&gf[cgi * 4], (u32)(t + 1), __ATOMIC_RELAXED,
                           __HIP_MEMORY_SCOPE_AGENT);
    }

    if (tid < 256) {
      // z-store AFTER the flag publish: not on anyone's critical path
      z[((size_t)m * TT + t) * HH + col] = h;
      if (t == TT - 1) hout[(size_t)m * HH + col] = h;
    }
  }
  if (tid < 256) memout[(size_t)m * HH + col] = memv;
}

extern "C" void kernel_launch(void* const* d_in, const int* in_sizes, int n_in,
                              void* d_out, int out_size, void* d_ws, size_t ws_size,
                              hipStream_t stream) {
  const float* x    = (const float*)d_in[0];
  const float* W    = (const float*)d_in[1];
  const float* bias = (const float*)d_in[2];

  float* z      = (float*)d_out;
  float* hout   = z + (size_t)NB * TT * HH;
  float* memout = hout + (size_t)NB * HH;

  u16* wp = (u16*)d_ws;
  u16* xp = wp + WPACK_SZ;
  u16* hp = xp + XPACK_SZ;
  u32* flags = (u32*)(hp + HPACK_SZ);

  hipLaunchKernelGGL(pack_w, dim3(2048), dim3(256), 0, stream, W, wp);
  hipLaunchKernelGGL(pack_x, dim3(8192), dim3(256), 0, stream, x, xp);
  hipLaunchKernelGGL(init_state, dim3(1), dim3(256), 0, stream, flags);

  hipLaunchKernelGGL(lstm_main, dim3(NBLK), dim3(512), 0, stream,
                     wp, xp, (u32*)hp, bias, z, hout, memout, flags);
}

// Round 14
// 1055.083 us; speedup vs baseline: 2.3954x; 1.2514x over previous
//
#include <hip/hip_runtime.h>

typedef unsigned short u16;
typedef unsigned int   u32;
typedef __attribute__((ext_vector_type(8))) short bf16x8;
typedef __attribute__((ext_vector_type(4))) float f32x4;

#define NB 64
#define TT 256
#define FF 1024
#define HH 1024
#define KK 2048
#define GG 4096
#define NBLK 256

// ws layout in u16 units
#define WPACK_SZ  (KK*GG)                    // 8388608 u16 = 16 MB
#define XPACK_SZ  ((size_t)NB*TT*FF)         // 16777216 u16 = 32 MB
#define HPACK_SZ  (2*4*32*64*8)              // 131072 u16 = 256 KB (double buffer)
#define FLAGS_SZ  (4*64*4)                   // u32: 4 rt-groups x 64 flags, 16B stride

__device__ __forceinline__ u16 f2bf(float f) {
  u32 u = __float_as_uint(f);
  u32 r = (u + 0x7FFFu + ((u >> 16) & 1u)) >> 16;
  return (u16)r;
}

// Pack W [K=2048][G=4096] fp32 -> B-fragment order:
// wp[((ct*64 + kt)*64 + l)*8 + j] = bf16( W[kt*32 + (l>>4)*8 + j][ct*16 + (l&15)] )
__global__ void pack_w(const float* __restrict__ W, u16* __restrict__ wp) {
  int tid = blockIdx.x * blockDim.x + threadIdx.x;   // 524288 threads
  if (tid >= (KK * GG / 16)) return;
  int j  = tid & 7;
  int g  = (tid >> 3) & 3;
  int kt = (tid >> 5) & 63;
  int ct = tid >> 11;                                // 0..255
  int k  = kt * 32 + g * 8 + j;
  const float* src = W + (size_t)k * GG + ct * 16;
  u16* dst = wp + (size_t)(ct * 64 + kt) * 512 + j;
  float4 v0 = *(const float4*)(src + 0);
  float4 v1 = *(const float4*)(src + 4);
  float4 v2 = *(const float4*)(src + 8);
  float4 v3 = *(const float4*)(src + 12);
  float vv[16] = {v0.x,v0.y,v0.z,v0.w, v1.x,v1.y,v1.z,v1.w,
                  v2.x,v2.y,v2.z,v2.w, v3.x,v3.y,v3.z,v3.w};
  #pragma unroll
  for (int c = 0; c < 16; ++c) dst[(size_t)(g * 16 + c) * 8] = f2bf(vv[c]);
}

// Pack x [N][T][F] fp32 -> A-fragment order per (t, rt):
// xp[(((t*4 + rt)*32 + kt)*64 + l)*8 + j] = bf16( x[16rt + (l&15)][t][kt*32 + (l>>4)*8 + j] )
__global__ void pack_x(const float* __restrict__ X, u16* __restrict__ xp) {
  int tid = blockIdx.x * blockDim.x + threadIdx.x;   // 2097152 threads
  if (tid >= (int)(NB * TT * FF / 8)) return;
  int l  = tid & 63;
  int kt = (tid >> 6) & 31;
  int rt = (tid >> 11) & 3;
  int t  = tid >> 13;                                // 0..255
  int n  = rt * 16 + (l & 15);
  int f  = kt * 32 + (l >> 4) * 8;
  const float* src = X + (size_t)n * TT * FF + (size_t)t * FF + f;
  float4 a = *(const float4*)(src);
  float4 b = *(const float4*)(src + 4);
  u16 tmp[8] = { f2bf(a.x), f2bf(a.y), f2bf(a.z), f2bf(a.w),
                 f2bf(b.x), f2bf(b.y), f2bf(b.z), f2bf(b.w) };
  *(uint4*)(xp + (size_t)((t * 4 + rt) * 32 + kt) * 512 + l * 8) = *(uint4*)tmp;
}

// zero barrier flags through the coherence point (ws is poisoned 0xAA; stale
// flags from a previous replay would open barriers spuriously)
__global__ void init_state(u32* __restrict__ flags) {
  int tid = threadIdx.x;
  #pragma unroll
  for (int i = 0; i < 4; ++i)
    __hip_atomic_store(&flags[i * 256 + tid], 0u, __ATOMIC_RELAXED,
                       __HIP_MEMORY_SCOPE_AGENT);
}

__launch_bounds__(1024, 1)  // 16 waves = 4 waves/SIMD (VGPR budget 128/wave)
__global__ void lstm_main(const u16* __restrict__ wp, const u16* __restrict__ xp,
                          u32* __restrict__ hp32, const float* __restrict__ bias,
                          float* __restrict__ z, float* __restrict__ hout,
                          float* __restrict__ memout, u32* flags) {
  const int b   = blockIdx.x;        // 256 blocks, all co-resident
  const int cgi = b & 63;            // col-group: 16 h-cols
  const int rt  = b >> 6;            // row-tile: 16 batch rows -> barrier group
  const int tid = threadIdx.x;
  const int w16 = tid >> 6;          // wave 0..15
  const int g   = w16 & 3;           // gate index
  const int s   = w16 >> 2;          // K-quarter: kt [8s, 8s+8) of each GEMM
  const int l   = tid & 63;
  const int ct  = g * 64 + cgi;      // global col-tile 0..255

  const u16* bp = wp + (size_t)ct * 32768 + l * 8;   // 64 kt * 512 per col-tile
  const float bv = (s == 0) ? bias[ct * 16 + (l & 15)] : 0.f;
  u32* gf = flags + rt * 256;        // this rt-group's 64 flags, stride 4 u32

  __shared__ u32   hs32[8192];       // 32 KB staged h fragments (this rt group)
  __shared__ float gl[4][4][16][16]; // partial gate tiles [K-quarter][gate]

  const int er  = tid >> 4;          // 0..15 epilogue row   (valid for tid<256)
  const int ec  = tid & 15;          // 0..15 epilogue col
  const int m   = rt * 16 + er;      // batch row
  const int col = cgi * 16 + ec;     // col within gate [0,1024)
  // hp u32 slot for the (even) col pair this thread's pair-store covers
  const int col0 = col & ~1;
  const int kt2  = col0 >> 5;
  const int g2   = (col0 >> 3) & 3;
  const int l2   = er | (g2 << 4);
  const int cbase = kt2 * 256 + l2 * 4 + ((col0 & 7) >> 1);  // u32 units

  float memv = 0.0f;                 // cell state (tid<256 only)

  for (int t = 0; t < TT; ++t) {
    const int p = t & 1;             // h(t) lives in buffer p (written last step)
    const u16* ax = xp + (size_t)((t * 4 + rt) * 32 + s * 8) * 512 + l * 8;
    const u16* bx = bp + (size_t)(s * 8) * 512;          // x-B frags, this quarter
    const u16* bh = bp + (size_t)(32 + s * 8) * 512;     // h-B frags, this quarter

    // ---- x GEMM: 8 MFMAs over this wave's K-quarter ----
    f32x4 acc0 = {bv, bv, bv, bv};
    f32x4 acc1 = {0.f, 0.f, 0.f, 0.f};
    #pragma unroll
    for (int kt = 0; kt < 8; kt += 2) {
      bf16x8 a0 = *(const bf16x8*)(ax + (size_t)kt * 512);
      bf16x8 b0 = *(const bf16x8*)(bx + (size_t)kt * 512);
      bf16x8 a1 = *(const bf16x8*)(ax + (size_t)(kt + 1) * 512);
      bf16x8 b1 = *(const bf16x8*)(bx + (size_t)(kt + 1) * 512);
      acc0 = __builtin_amdgcn_mfma_f32_16x16x32_bf16(a0, b0, acc0, 0, 0, 0);
      acc1 = __builtin_amdgcn_mfma_f32_16x16x32_bf16(a1, b1, acc1, 0, 0, 0);
    }

    if (t != 0) {
      // ---- wait for h(t): coalesced poll of the 64 group flags ----
      const u32 tgt = (u32)t;
      for (;;) {
        u32 v = __hip_atomic_load(&gf[l * 4], __ATOMIC_RELAXED,
                                  __HIP_MEMORY_SCOPE_AGENT);
        if (l == cgi) v = tgt;       // own arrival known locally
        if (!__any((int)(v < tgt))) break;
        __builtin_amdgcn_s_sleep(1);
      }

      // ---- copy h fragments to LDS (1024 threads, 8 words each) ----
      const u32* hsrc = hp32 + (size_t)(p * 4 + rt) * 8192;
      u32 tmpv[8];
      #pragma unroll
      for (int i = 0; i < 8; ++i)
        tmpv[i] = __hip_atomic_load(hsrc + i * 1024 + tid, __ATOMIC_RELAXED,
                                    __HIP_MEMORY_SCOPE_AGENT);
      #pragma unroll
      for (int i = 0; i < 8; ++i)
        hs32[i * 1024 + tid] = tmpv[i];
      __syncthreads();

      // ---- h GEMM: 8 MFMAs, A from LDS, B from L2 ----
      const char* hb = (const char*)hs32 + (size_t)(s * 8) * 1024 + l * 16;
      #pragma unroll
      for (int kt = 0; kt < 8; kt += 2) {
        bf16x8 a0 = *(const bf16x8*)(hb + (size_t)kt * 1024);
        bf16x8 b0 = *(const bf16x8*)(bh + (size_t)kt * 512);
        bf16x8 a1 = *(const bf16x8*)(hb + (size_t)(kt + 1) * 1024);
        bf16x8 b1 = *(const bf16x8*)(bh + (size_t)(kt + 1) * 512);
        acc0 = __builtin_amdgcn_mfma_f32_16x16x32_bf16(a0, b0, acc0, 0, 0, 0);
        acc1 = __builtin_amdgcn_mfma_f32_16x16x32_bf16(a1, b1, acc1, 0, 0, 0);
      }
    }

    // C-layout: col = l&15, row = (l>>4)*4 + r  (HW-verified)
    #pragma unroll
    for (int r = 0; r < 4; ++r)
      gl[s][g][(l >> 4) * 4 + r][l & 15] = acc0[r] + acc1[r];
    __syncthreads();

    float h;
    if (tid < 256) {
      // gate combine: sum the four K-quarter partials per gate
      float ai = (gl[0][0][er][ec] + gl[1][0][er][ec]) +
                 (gl[2][0][er][ec] + gl[3][0][er][ec]);
      float af = (gl[0][1][er][ec] + gl[1][1][er][ec]) +
                 (gl[2][1][er][ec] + gl[3][1][er][ec]);
      float ao = (gl[0][2][er][ec] + gl[1][2][er][ec]) +
                 (gl[2][2][er][ec] + gl[3][2][er][ec]);
      float ag = (gl[0][3][er][ec] + gl[1][3][er][ec]) +
                 (gl[2][3][er][ec] + gl[3][3][er][ec]);
      float si = 1.f / (1.f + __expf(-ai));
      float sf = 1.f / (1.f + __expf(-af));
      float so = 1.f / (1.f + __expf(-ao));
      float tg = 1.f - 2.f / (__expf(2.f * ag) + 1.f);   // safe tanh
      memv = sf * memv + si * tg;
      float th = 1.f - 2.f / (__expf(2.f * memv) + 1.f); // safe tanh
      h = so * th;

      // publish h as bf16 pairs through the coherence point (write-through)
      float hn = __shfl_xor(h, 1);   // partner col's h
      if ((ec & 1) == 0) {
        u32 pair = (u32)f2bf(h) | ((u32)f2bf(hn) << 16);
        __hip_atomic_store(&hp32[(size_t)((p ^ 1) * 4 + rt) * 8192 + cbase], pair,
                           __ATOMIC_RELAXED, __HIP_MEMORY_SCOPE_AGENT);
      }
    }

    if (t < TT - 1) {
      // publish: syncthreads drains vmcnt(0) -> hp data at coherence point.
      // (also separates this step's hs32/gl reads from next step's writes)
      __syncthreads();
      if (tid == 0)
        __hip_atomic_store(&gf[cgi * 4], (u32)(t + 1), __ATOMIC_RELAXED,
                           __HIP_MEMORY_SCOPE_AGENT);
    }

    if (tid < 256) {
      // z-store AFTER the flag publish: not on anyone's critical path
      z[((size_t)m * TT + t) * HH + col] = h;
      if (t == TT - 1) hout[(size_t)m * HH + col] = h;
    }
  }
  if (tid < 256) memout[(size_t)m * HH + col] = memv;
}

extern "C" void kernel_launch(void* const* d_in, const int* in_sizes, int n_in,
                              void* d_out, int out_size, void* d_ws, size_t ws_size,
                              hipStream_t stream) {
  const float* x    = (const float*)d_in[0];
  const float* W    = (const float*)d_in[1];
  const float* bias = (const float*)d_in[2];

  float* z      = (float*)d_out;
  float* hout   = z + (size_t)NB * TT * HH;
  float* memout = hout + (size_t)NB * HH;

  u16* wp = (u16*)d_ws;
  u16* xp = wp + WPACK_SZ;
  u16* hp = xp + XPACK_SZ;
  u32* flags = (u32*)(hp + HPACK_SZ);

  hipLaunchKernelGGL(pack_w, dim3(2048), dim3(256), 0, stream, W, wp);
  hipLaunchKernelGGL(pack_x, dim3(8192), dim3(256), 0, stream, x, xp);
  hipLaunchKernelGGL(init_state, dim3(1), dim3(256), 0, stream, flags);

  hipLaunchKernelGGL(lstm_main, dim3(NBLK), dim3(1024), 0, stream,
                     wp, xp, (u32*)hp, bias, z, hout, memout, flags);
}